// Round 1
// baseline (626.173 us; speedup 1.0000x reference)
//
#include <hip/hip_runtime.h>
#include <hip/hip_bf16.h>
#include <stdint.h>

#define M_DIM 4096
#define K_DIM 4096
#define N_DIM 2048
#define B_DIM 4
#define NNZ_PER_ROW 409
#define NNZ_TOT (M_DIM * NNZ_PER_ROW)

typedef unsigned short u16;
typedef short short8 __attribute__((ext_vector_type(8)));
typedef float f32x4 __attribute__((ext_vector_type(4)));

__device__ __forceinline__ u16 f2bf(float f) {
    __hip_bfloat16 h = __float2bfloat16(f);
    u16 s;
    __builtin_memcpy(&s, &h, 2);
    return s;
}

// async global->LDS, 16 bytes per lane; LDS dest = wave-uniform base + lane*16
__device__ __forceinline__ void lds16(const u16* g, u16* l) {
    __builtin_amdgcn_global_load_lds(
        (__attribute__((address_space(1))) void*)g,
        (__attribute__((address_space(3))) void*)l,
        16, 0, 0);
}

// ---------------------------------------------------------------------------
// Kernel 1: x fp32 -> bf16 (flat, layout-preserving). 8 floats / thread.
// ---------------------------------------------------------------------------
__global__ void cvt_x(const float* __restrict__ in, u16* __restrict__ out) {
    int i = blockIdx.x * blockDim.x + threadIdx.x;  // handles 8 elements
    const float4* in4 = reinterpret_cast<const float4*>(in) + (size_t)i * 2;
    float4 a = in4[0];
    float4 b = in4[1];
    union { u16 u[8]; uint4 v; } o;
    o.u[0] = f2bf(a.x); o.u[1] = f2bf(a.y); o.u[2] = f2bf(a.z); o.u[3] = f2bf(a.w);
    o.u[4] = f2bf(b.x); o.u[5] = f2bf(b.y); o.u[6] = f2bf(b.z); o.u[7] = f2bf(b.w);
    reinterpret_cast<uint4*>(out)[i] = o.v;
}

// ---------------------------------------------------------------------------
// Kernel 2: scatter CSR -> dense bf16 W [M][K].
// Columns are sorted within each row, so duplicates are adjacent runs:
// only the first element of a run writes (sum of the run), others skip.
// W must be pre-zeroed (memset on stream).
// ---------------------------------------------------------------------------
__global__ void scatter_w(const float* __restrict__ vals,
                          const int* __restrict__ cols,
                          u16* __restrict__ W) {
    int j = blockIdx.x * blockDim.x + threadIdx.x;
    if (j >= NNZ_TOT) return;
    int row = j / NNZ_PER_ROW;
    int rs  = row * NNZ_PER_ROW;
    int c = cols[j];
    if (j > rs && cols[j - 1] == c) return;  // not first of its run
    float s = vals[j];
    int re = rs + NNZ_PER_ROW;
    for (int t = j + 1; t < re; ++t) {
        if (cols[t] != c) break;
        s += vals[t];
    }
    W[(size_t)row * K_DIM + c] = f2bf(s);
}

// ---------------------------------------------------------------------------
// Kernel 3: m97-style NT GEMM. A = W [M][K] bf16, Bt = x [B][N][K] bf16,
// C = out [B][M][N] fp32. 128x128 tile, BK=32, 4 waves (2x2), each wave a
// 4x4 grid of 16x16x32 bf16 MFMAs. global_load_lds width-16 staging.
// ---------------------------------------------------------------------------
__global__ __launch_bounds__(256) void gemm_bt(
    const u16* __restrict__ A,
    const u16* __restrict__ Bt,
    float* __restrict__ C) {
    __shared__ __align__(16) u16 sA[128][32];  // 8 KB
    __shared__ __align__(16) u16 sB[128][32];  // 8 KB

    const int tid  = threadIdx.x;
    const int wave = tid >> 6;
    const int lane = tid & 63;
    const int wm = wave >> 1, wn = wave & 1;   // 2x2 waves, 64x64 each
    const int bn0 = blockIdx.x * 128;
    const int bm0 = blockIdx.y * 128;
    const int bat = blockIdx.z;

    const u16* Ab = A + (size_t)bm0 * K_DIM;
    const u16* Bb = Bt + (size_t)bat * N_DIM * K_DIM + (size_t)bn0 * K_DIM;

    // staging decomposition: lane covers row lr = lane>>2, 8 elems at lc
    const int lr = lane >> 2;
    const int lc = (lane & 3) * 8;

    // fragment decomposition
    const int fm   = lane & 15;   // A-row / B-row (=n) within 16-tile
    const int quad = lane >> 4;   // 0..3
    const int kf   = quad * 8;    // k offset within BK=32

    f32x4 acc[4][4] = {};

    for (int k0 = 0; k0 < K_DIM; k0 += 32) {
        // each wave stages 32 rows of A and 32 rows of B (2 x 16-row groups)
        {
            const u16* ga0 = Ab + (size_t)(wave * 32 +      lr) * K_DIM + k0 + lc;
            const u16* ga1 = Ab + (size_t)(wave * 32 + 16 + lr) * K_DIM + k0 + lc;
            const u16* gb0 = Bb + (size_t)(wave * 32 +      lr) * K_DIM + k0 + lc;
            const u16* gb1 = Bb + (size_t)(wave * 32 + 16 + lr) * K_DIM + k0 + lc;
            lds16(ga0, &sA[wave * 32][0]);
            lds16(ga1, &sA[wave * 32 + 16][0]);
            lds16(gb0, &sB[wave * 32][0]);
            lds16(gb1, &sB[wave * 32 + 16][0]);
        }
        __syncthreads();

        short8 af[4], bfr[4];
#pragma unroll
        for (int i = 0; i < 4; ++i)
            af[i] = *(const short8*)&sA[wm * 64 + i * 16 + fm][kf];
#pragma unroll
        for (int j = 0; j < 4; ++j)
            bfr[j] = *(const short8*)&sB[wn * 64 + j * 16 + fm][kf];
#pragma unroll
        for (int i = 0; i < 4; ++i)
#pragma unroll
            for (int j = 0; j < 4; ++j)
                acc[i][j] = __builtin_amdgcn_mfma_f32_16x16x32_bf16(
                    af[i], bfr[j], acc[i][j], 0, 0, 0);
        __syncthreads();
    }

    // epilogue: C/D layout col = lane&15, row = quad*4 + reg  (m89-verified)
    float* Cb = C + (size_t)bat * M_DIM * N_DIM;
#pragma unroll
    for (int i = 0; i < 4; ++i) {
#pragma unroll
        for (int j = 0; j < 4; ++j) {
            int m0 = bm0 + wm * 64 + i * 16 + quad * 4;
            int n  = bn0 + wn * 64 + j * 16 + fm;
#pragma unroll
            for (int r = 0; r < 4; ++r)
                Cb[(size_t)(m0 + r) * N_DIM + n] = acc[i][j][r];
        }
    }
}

extern "C" void kernel_launch(void* const* d_in, const int* in_sizes, int n_in,
                              void* d_out, int out_size, void* d_ws, size_t ws_size,
                              hipStream_t stream) {
    const float* x    = (const float*)d_in[0];
    const float* vals = (const float*)d_in[1];
    // d_in[2] = row_offsets (structure is fixed: row i starts at i*409)
    const int*   cols = (const int*)d_in[3];
    float* out = (float*)d_out;

    // workspace layout: [ W bf16 : M*K*2 = 32 MB ][ Xb bf16 : B*N*K*2 = 64 MB ]
    u16* W  = (u16*)d_ws;
    u16* Xb = (u16*)d_ws + (size_t)M_DIM * K_DIM;

    // zero W (ws is poisoned 0xAA before every call)
    hipMemsetAsync(W, 0, (size_t)M_DIM * K_DIM * sizeof(u16), stream);

    // convert x to bf16
    int n8 = (B_DIM * N_DIM * K_DIM) / 8;  // 4,194,304 threads
    cvt_x<<<dim3(n8 / 256), dim3(256), 0, stream>>>(x, Xb);

    // scatter CSR into dense bf16 W
    scatter_w<<<dim3((NNZ_TOT + 255) / 256), dim3(256), 0, stream>>>(vals, cols, W);

    // dense NT GEMM per batch
    dim3 grid(N_DIM / 128, M_DIM / 128, B_DIM);
    gemm_bt<<<grid, dim3(256), 0, stream>>>(W, Xb, out);
}

// Round 2
// 550.435 us; speedup vs baseline: 1.1376x; 1.1376x over previous
//
#include <hip/hip_runtime.h>
#include <hip/hip_bf16.h>
#include <stdint.h>

#define M_DIM 4096
#define K_DIM 4096
#define N_DIM 2048
#define B_DIM 4
#define NNZ_PER_ROW 409
#define NNZ_TOT (M_DIM * NNZ_PER_ROW)

typedef unsigned short u16;
typedef short short8 __attribute__((ext_vector_type(8)));
typedef float f32x4 __attribute__((ext_vector_type(4)));

__device__ __forceinline__ u16 f2bf(float f) {
    __hip_bfloat16 h = __float2bfloat16(f);
    u16 s;
    __builtin_memcpy(&s, &h, 2);
    return s;
}

// async global->LDS, 16 bytes per lane; LDS dest = wave-uniform base + lane*16
__device__ __forceinline__ void lds16(const u16* g, u16* l) {
    __builtin_amdgcn_global_load_lds(
        (__attribute__((address_space(1))) void*)g,
        (__attribute__((address_space(3))) void*)l,
        16, 0, 0);
}

// ---------------------------------------------------------------------------
// Kernel 1: x fp32 -> bf16, fully coalesced: each lane reads 16 B (float4)
// contiguous, writes 8 B (4 x bf16) contiguous.
// ---------------------------------------------------------------------------
__global__ void cvt_x(const float* __restrict__ in, u16* __restrict__ out) {
    int i = blockIdx.x * blockDim.x + threadIdx.x;  // handles 4 elements
    float4 a = reinterpret_cast<const float4*>(in)[i];
    union { u16 u[4]; uint2 v; } o;
    o.u[0] = f2bf(a.x); o.u[1] = f2bf(a.y); o.u[2] = f2bf(a.z); o.u[3] = f2bf(a.w);
    reinterpret_cast<uint2*>(out)[i] = o.v;
}

// ---------------------------------------------------------------------------
// Kernel 2: scatter CSR -> dense bf16 W [M][K].
// Columns sorted within each row => duplicates are adjacent runs: first
// element of a run writes the run-sum, others skip. W pre-zeroed via memset.
// ---------------------------------------------------------------------------
__global__ void scatter_w(const float* __restrict__ vals,
                          const int* __restrict__ cols,
                          u16* __restrict__ W) {
    int j = blockIdx.x * blockDim.x + threadIdx.x;
    if (j >= NNZ_TOT) return;
    int row = j / NNZ_PER_ROW;
    int rs  = row * NNZ_PER_ROW;
    int c = cols[j];
    if (j > rs && cols[j - 1] == c) return;  // not first of its run
    float s = vals[j];
    int re = rs + NNZ_PER_ROW;
    for (int t = j + 1; t < re; ++t) {
        if (cols[t] != c) break;
        s += vals[t];
    }
    W[(size_t)row * K_DIM + c] = f2bf(s);
}

// ---------------------------------------------------------------------------
// Kernel 3: NT GEMM. A = W [M][K] bf16, Bt = x [B][N][K] bf16,
// C = out [B][M][N] fp32. 128x128 tile, BK=64, 4 waves (2x2), each wave a
// 4x4 grid of 16x16x32 bf16 MFMAs x 2 K-steps per iteration.
// LDS layout: row r (128 B) holds its 8 16-B chunks XOR-swizzled:
// global chunk c lives at position c ^ (r & 7). This makes the fragment
// ds_read_b128 2-way bank-aliased (free) instead of 8-way.
// ---------------------------------------------------------------------------
__global__ __launch_bounds__(256) void gemm_bt(
    const u16* __restrict__ A,
    const u16* __restrict__ Bt,
    float* __restrict__ C) {
    __shared__ __align__(16) u16 sA[128][64];  // 16 KB
    __shared__ __align__(16) u16 sB[128][64];  // 16 KB

    const int tid  = threadIdx.x;
    const int wave = tid >> 6;
    const int lane = tid & 63;
    const int wm = wave >> 1, wn = wave & 1;   // 2x2 waves, 64x64 each
    const int bn0 = blockIdx.x * 128;
    const int bm0 = blockIdx.y * 128;
    const int bat = blockIdx.z;

    const u16* Ab = A + (size_t)bm0 * K_DIM;
    const u16* Bb = Bt + (size_t)bat * N_DIM * K_DIM + (size_t)bn0 * K_DIM;

    // staging decomposition: per call, lane covers row (lane>>3) of an 8-row
    // group; its global 16-B chunk is (lane&7) ^ (lane>>3)  [the swizzle].
    const int slr = lane >> 3;                  // 0..7 local row
    const int slc = ((lane & 7) ^ slr) * 8;     // swizzled source col (elems)

    // fragment decomposition
    const int fm   = lane & 15;   // A-row / B-row (=n) within 16-tile
    const int quad = lane >> 4;   // 0..3
    const int key  = fm & 7;      // swizzle key (row & 7, uniform over i-tiles)
    const int c0   = (quad ^ key) * 8;          // chunk for K-step 0 (elems)
    const int c1   = ((quad + 4) ^ key) * 8;    // chunk for K-step 1

    f32x4 acc[4][4] = {};

    for (int k0 = 0; k0 < K_DIM; k0 += 64) {
        // each wave stages its 32 rows of A and of B: 4 calls each, 8 rows/call
#pragma unroll
        for (int g = 0; g < 4; ++g) {
            int r = wave * 32 + g * 8;
            lds16(Ab + (size_t)(r + slr) * K_DIM + k0 + slc, &sA[r][0]);
            lds16(Bb + (size_t)(r + slr) * K_DIM + k0 + slc, &sB[r][0]);
        }
        __syncthreads();

        // K-step 0
        {
            short8 af[4], bfr[4];
#pragma unroll
            for (int i = 0; i < 4; ++i)
                af[i] = *(const short8*)&sA[wm * 64 + i * 16 + fm][c0];
#pragma unroll
            for (int j = 0; j < 4; ++j)
                bfr[j] = *(const short8*)&sB[wn * 64 + j * 16 + fm][c0];
#pragma unroll
            for (int i = 0; i < 4; ++i)
#pragma unroll
                for (int j = 0; j < 4; ++j)
                    acc[i][j] = __builtin_amdgcn_mfma_f32_16x16x32_bf16(
                        af[i], bfr[j], acc[i][j], 0, 0, 0);
        }
        // K-step 1
        {
            short8 af[4], bfr[4];
#pragma unroll
            for (int i = 0; i < 4; ++i)
                af[i] = *(const short8*)&sA[wm * 64 + i * 16 + fm][c1];
#pragma unroll
            for (int j = 0; j < 4; ++j)
                bfr[j] = *(const short8*)&sB[wn * 64 + j * 16 + fm][c1];
#pragma unroll
            for (int i = 0; i < 4; ++i)
#pragma unroll
                for (int j = 0; j < 4; ++j)
                    acc[i][j] = __builtin_amdgcn_mfma_f32_16x16x32_bf16(
                        af[i], bfr[j], acc[i][j], 0, 0, 0);
        }
        __syncthreads();
    }

    // epilogue: C/D layout col = lane&15, row = quad*4 + reg  (m89-verified)
    float* Cb = C + (size_t)bat * M_DIM * N_DIM;
#pragma unroll
    for (int i = 0; i < 4; ++i) {
#pragma unroll
        for (int j = 0; j < 4; ++j) {
            int m0 = bm0 + wm * 64 + i * 16 + quad * 4;
            int n  = bn0 + wn * 64 + j * 16 + fm;
#pragma unroll
            for (int r = 0; r < 4; ++r)
                Cb[(size_t)(m0 + r) * N_DIM + n] = acc[i][j][r];
        }
    }
}

extern "C" void kernel_launch(void* const* d_in, const int* in_sizes, int n_in,
                              void* d_out, int out_size, void* d_ws, size_t ws_size,
                              hipStream_t stream) {
    const float* x    = (const float*)d_in[0];
    const float* vals = (const float*)d_in[1];
    // d_in[2] = row_offsets (structure fixed: row i starts at i*409)
    const int*   cols = (const int*)d_in[3];
    float* out = (float*)d_out;

    // workspace: [ W bf16 : 32 MB ][ Xb bf16 : 64 MB ]
    u16* W  = (u16*)d_ws;
    u16* Xb = (u16*)d_ws + (size_t)M_DIM * K_DIM;

    hipMemsetAsync(W, 0, (size_t)M_DIM * K_DIM * sizeof(u16), stream);

    int n4 = (B_DIM * N_DIM * K_DIM) / 4;  // 8,388,608 threads
    cvt_x<<<dim3(n4 / 256), dim3(256), 0, stream>>>(x, Xb);

    scatter_w<<<dim3((NNZ_TOT + 255) / 256), dim3(256), 0, stream>>>(vals, cols, W);

    dim3 grid(N_DIM / 128, M_DIM / 128, B_DIM);
    gemm_bt<<<grid, dim3(256), 0, stream>>>(W, Xb, out);
}